// Round 4
// baseline (691.061 us; speedup 1.0000x reference)
//
#include <hip/hip_runtime.h>
#include <math.h>

// Problem constants
#define kB 32768
#define kD 2048
#define kH 1024
#define kL 384
#define kP 192
#define kC 10
#define kNP 2
#define kND 2
#define kNCAT 768
#define kTAU 0.1f
#define kEPS 1e-5f
#define NPART 256                 // stats partials: 2 per 256-row block * 128 blocks
#define SCALE 64.0f               // operand pre-scale (keeps f16 lo-plane normal)
#define INV_SC2 (1.0f / 4096.0f)  // GEMM outputs carry SCALE^2

typedef _Float16 f16x8 __attribute__((ext_vector_type(8)));
typedef _Float16 f16x4 __attribute__((ext_vector_type(4)));
typedef float f32x16 __attribute__((ext_vector_type(16)));

// async global->LDS, 16B per lane (linear LDS dest: base + lane*16)
__device__ __forceinline__ void gll16(const unsigned short* g, unsigned short* l)
{
    __builtin_amdgcn_global_load_lds(
        (const __attribute__((address_space(1))) unsigned int*)g,
        (__attribute__((address_space(3))) unsigned int*)l, 16, 0, 0);
}

// bank swizzle key: 8 chunk slots per 128B row, key mixes row bits [2:0]^[5:3]
__device__ __host__ __forceinline__ int key8(int r) { return (r ^ (r >> 3)) & 7; }

// ---------------------------------------------------------------------------
// split_pack (weights only): fp32 [rows][K] -> packed f16 hi/lo planes,
// pre-swizzled. Per 32-k block: 8 chunks of 16B; logical 0..3 hi, 4..7 lo;
// stored chunk = logical ^ key8(row). Values scaled by 64.
// ---------------------------------------------------------------------------
__global__ __launch_bounds__(256)
void split_pack(const float* __restrict__ in, unsigned short* __restrict__ out, int K)
{
    const int row = blockIdx.x;
    const int t = threadIdx.x;
    const int s = key8(row);
    const float* ir = in + (size_t)row * K;
    unsigned short* orow = out + (size_t)row * (K * 2);
    for (int k0 = t * 4; k0 < K; k0 += 1024) {
        const float4 v = *(const float4*)&ir[k0];
        const float a0 = v.x * SCALE, a1 = v.y * SCALE, a2 = v.z * SCALE, a3 = v.w * SCALE;
        const _Float16 h0 = (_Float16)a0, h1 = (_Float16)a1, h2 = (_Float16)a2, h3 = (_Float16)a3;
        const _Float16 l0 = (_Float16)(a0 - (float)h0), l1 = (_Float16)(a1 - (float)h1);
        const _Float16 l2 = (_Float16)(a2 - (float)h2), l3 = (_Float16)(a3 - (float)h3);
        const f16x4 hi = {h0, h1, h2, h3};
        const f16x4 lo = {l0, l1, l2, l3};
        const int kb = k0 >> 5, kk = k0 & 31;
        const int c = kk >> 3, off = kk & 7;
        *(f16x4*)&orow[kb * 64 + ((c ^ s) << 3) + off]       = hi;
        *(f16x4*)&orow[kb * 64 + (((c ^ 4) ^ s) << 3) + off] = lo;
    }
}

// ---------------------------------------------------------------------------
// Fused split-f16 MFMA GEMM, 256x256 tile, 8 waves (2x4), BK=32,
// v_mfma_f32_32x32x16_f16 (4x2 fragments of 32x32 per wave = 128x64 out).
// A: fp32 source, reg-staged (optional fused BN+ReLU), split hi/lo, ds_write
//    with key8 XOR chunk swizzle. B: pre-packed, global_load_lds (linear).
// Double-buffered LDS, single barrier per K-step. Epilogue: C store + fused
// column partial sums/sumsq into psum/psumsq[256][statN].
// ---------------------------------------------------------------------------
template<int KDIM, bool BN>
__global__ __launch_bounds__(512, 1)
void gemm_fused(const float* __restrict__ Afp,
                const unsigned short* __restrict__ Bpk,
                const float* __restrict__ bnsc, const float* __restrict__ bnsh,
                float* __restrict__ C, const int N, const int gridX,
                float* __restrict__ psum, float* __restrict__ psumsq, const int statN)
{
    constexpr int NKB = KDIM / 32;
    __shared__ unsigned short lds[4][256 * 64];   // [0]=A0 [1]=A1 [2]=B0 [3]=B1

    const int t = threadIdx.x;
    const int lane = t & 63;
    const int w = t >> 6;                // 0..7
    const int wr = w >> 2, wc = w & 3;   // 2x4 wave grid; per-wave 128x64
    const int l31 = lane & 31, kg = lane >> 5;

    // XCD-chunked swizzle (bijective: nwg % 8 == 0)
    const int nwg = gridDim.x;
    const int chunk = nwg >> 3;
    const int bid = blockIdx.x;
    const int logical = (bid & 7) * chunk + (bid >> 3);
    const int bx = logical % gridX, by = logical / gridX;
    const int m0 = by * 256, n0 = bx * 256;

    // A staging: thread -> (row, k-half)
    const int arow = t >> 1;
    const int akh = t & 1;
    const int skey = key8(arow);
    const int c0 = akh * 2, c1 = akh * 2 + 1;
    const float* aSrc = Afp + (size_t)(m0 + arow) * KDIM + akh * 16;

    // B staging: wave w, issue it: 64 chunks (8 rows) per gll16 group
    const size_t bstride = (size_t)NKB * 64;
    const unsigned short* bG[4];
    int bLoff[4];
#pragma unroll
    for (int it = 0; it < 4; ++it) {
        const int Q = (w * 4 + it) * 64 + lane;
        bG[it] = Bpk + (size_t)(n0 + (Q >> 3)) * bstride + (Q & 7) * 8;
        bLoff[it] = (w * 4 + it) * 512;
    }

    // fragment read swizzle keys (tile-row based; 32 rows per fragment)
    int keyA[4], keyB[2];
#pragma unroll
    for (int mi = 0; mi < 4; ++mi)
        keyA[mi] = (l31 & 7) ^ ((mi * 4 + (l31 >> 3)) & 7);
#pragma unroll
    for (int ni = 0; ni < 2; ++ni)
        keyB[ni] = (l31 & 7) ^ ((wc * 8 + ni * 4 + (l31 >> 3)) & 7);

    f32x16 acc[4][2];
#pragma unroll
    for (int mi = 0; mi < 4; ++mi)
#pragma unroll
        for (int ni = 0; ni < 2; ++ni)
#pragma unroll
            for (int r = 0; r < 16; ++r) acc[mi][ni][r] = 0.f;

    float4 av[4], scv[4], shv[4];

    auto stage_issue = [&](int kb, int buf) {
        const int kt = kb * 32;
#pragma unroll
        for (int it = 0; it < 4; ++it)
            gll16(bG[it] + (size_t)kb * 64, &lds[2 + buf][bLoff[it]]);
#pragma unroll
        for (int j = 0; j < 4; ++j)
            av[j] = *(const float4*)&aSrc[kt + j * 4];
        if constexpr (BN) {
#pragma unroll
            for (int j = 0; j < 4; ++j) {
                scv[j] = *(const float4*)&bnsc[kt + akh * 16 + j * 4];
                shv[j] = *(const float4*)&bnsh[kt + akh * 16 + j * 4];
            }
        }
    };

    auto stage_write = [&](int buf) {
        float v[16];
#pragma unroll
        for (int j = 0; j < 4; ++j) {
            float4 a = av[j];
            if constexpr (BN) {
                a.x = fmaxf(fmaf(a.x, scv[j].x, shv[j].x), 0.f);
                a.y = fmaxf(fmaf(a.y, scv[j].y, shv[j].y), 0.f);
                a.z = fmaxf(fmaf(a.z, scv[j].z, shv[j].z), 0.f);
                a.w = fmaxf(fmaf(a.w, scv[j].w, shv[j].w), 0.f);
            } else {
                a.x *= SCALE; a.y *= SCALE; a.z *= SCALE; a.w *= SCALE;
            }
            v[j * 4 + 0] = a.x; v[j * 4 + 1] = a.y;
            v[j * 4 + 2] = a.z; v[j * 4 + 3] = a.w;
        }
        f16x8 hi[2], lo[2];
#pragma unroll
        for (int h = 0; h < 2; ++h)
#pragma unroll
            for (int i = 0; i < 8; ++i) {
                const float x = v[h * 8 + i];
                const _Float16 hh = (_Float16)x;
                hi[h][i] = hh;
                lo[h][i] = (_Float16)(x - (float)hh);
            }
        unsigned short* dst = &lds[buf][arow * 64];
        *(f16x8*)&dst[(c0 ^ skey) * 8]       = hi[0];
        *(f16x8*)&dst[(c1 ^ skey) * 8]       = hi[1];
        *(f16x8*)&dst[((c0 ^ 4) ^ skey) * 8] = lo[0];
        *(f16x8*)&dst[((c1 ^ 4) ^ skey) * 8] = lo[1];
    };

    // prologue: stage tile 0 into buffer 0
    stage_issue(0, 0);
    stage_write(0);
    asm volatile("s_waitcnt vmcnt(0) lgkmcnt(0)" ::: "memory");
    __builtin_amdgcn_s_barrier();

    for (int kb = 0; kb < NKB; ++kb) {
        const int cur = kb & 1, nxt = cur ^ 1;
        const bool pf = (kb + 1 < NKB);
        if (pf) stage_issue(kb + 1, nxt);    // loads fly during MFMA phase

        // B fragments: [ni][ksub] hi/lo; logical chunk = ksub*2 + kg (+4 lo)
        f16x8 bh[2][2], bl[2][2];
#pragma unroll
        for (int ni = 0; ni < 2; ++ni) {
            const unsigned short* bb = &lds[2 + cur][(wc * 64 + ni * 32 + l31) * 64];
#pragma unroll
            for (int ks = 0; ks < 2; ++ks) {
                const int lg = ks * 2 + kg;
                bh[ni][ks] = *(const f16x8*)&bb[((lg ^ keyB[ni]) << 3)];
                bl[ni][ks] = *(const f16x8*)&bb[(((lg ^ 4) ^ keyB[ni]) << 3)];
            }
        }
#pragma unroll
        for (int mi = 0; mi < 4; ++mi) {
            const unsigned short* ab = &lds[cur][(wr * 128 + mi * 32 + l31) * 64];
            f16x8 ah[2], al[2];
#pragma unroll
            for (int ks = 0; ks < 2; ++ks) {
                const int lg = ks * 2 + kg;
                ah[ks] = *(const f16x8*)&ab[((lg ^ keyA[mi]) << 3)];
                al[ks] = *(const f16x8*)&ab[(((lg ^ 4) ^ keyA[mi]) << 3)];
            }
#pragma unroll
            for (int ni = 0; ni < 2; ++ni)
#pragma unroll
                for (int ks = 0; ks < 2; ++ks) {
                    acc[mi][ni] = __builtin_amdgcn_mfma_f32_32x32x16_f16(ah[ks], bh[ni][ks], acc[mi][ni], 0, 0, 0);
                    acc[mi][ni] = __builtin_amdgcn_mfma_f32_32x32x16_f16(ah[ks], bl[ni][ks], acc[mi][ni], 0, 0, 0);
                    acc[mi][ni] = __builtin_amdgcn_mfma_f32_32x32x16_f16(al[ks], bh[ni][ks], acc[mi][ni], 0, 0, 0);
                }
        }
        if (pf) stage_write(nxt);
        asm volatile("s_waitcnt vmcnt(0) lgkmcnt(0)" ::: "memory");
        __builtin_amdgcn_s_barrier();
    }

    // C store: col = lane&31, row = (reg&3) + 8*(reg>>2) + 4*(lane>>5)
#pragma unroll
    for (int mi = 0; mi < 4; ++mi)
#pragma unroll
        for (int ni = 0; ni < 2; ++ni) {
            const int colg = n0 + wc * 64 + ni * 32 + l31;
#pragma unroll
            for (int r = 0; r < 16; ++r) {
                const int row = m0 + wr * 128 + mi * 32 + (r & 3) + 8 * (r >> 2) + 4 * kg;
                C[(size_t)row * N + colg] = acc[mi][ni][r];
            }
        }

    // fused column partial stats over this wave's 128 rows
#pragma unroll
    for (int ni = 0; ni < 2; ++ni) {
        float s = 0.f, sq = 0.f;
#pragma unroll
        for (int mi = 0; mi < 4; ++mi)
#pragma unroll
            for (int r = 0; r < 16; ++r) {
                const float v = acc[mi][ni][r];
                s += v;
                sq = fmaf(v, v, sq);
            }
        s  += __shfl_xor(s, 32);
        sq += __shfl_xor(sq, 32);
        const int col = n0 + wc * 64 + ni * 32 + l31;
        if (lane < 32 && col < statN) {
            psum[(size_t)(by * 2 + wr) * statN + col]   = s;
            psumsq[(size_t)(by * 2 + wr) * statN + col] = sq;
        }
    }
}

// ---------------------------------------------------------------------------
// finalize: input partials of Z' = Z/inv_sc; output scale/shift s.t.
// Z'*scale + shift == outsc * (BN(Z)*g + be)
// ---------------------------------------------------------------------------
__global__ __launch_bounds__(256)
void colstat_finalize(const float* __restrict__ psum, const float* __restrict__ psumsq,
                      int ncols, const float* __restrict__ g, const float* __restrict__ be,
                      float* __restrict__ scale, float* __restrict__ shift,
                      float inv_sc, float outsc)
{
    const int c = blockIdx.x * 256 + threadIdx.x;
    if (c >= ncols) return;
    float s = 0.f, sq = 0.f;
    for (int i = 0; i < NPART; ++i) {
        s  += psum[(size_t)i * ncols + c];
        sq += psumsq[(size_t)i * ncols + c];
    }
    const float mup = s * (1.f / kB);
    const float var = (sq * (1.f / kB) - mup * mup) * inv_sc * inv_sc;
    const float scl = outsc * g[c] * rsqrtf(var + kEPS) * inv_sc;
    scale[c] = scl;
    shift[c] = fmaf(-mup, scl, outsc * be[c]);
}

// ---------------------------------------------------------------------------
// Tail: per-row BN2+ReLU -> dom, sw, gumbel routing, selected expert.
// ---------------------------------------------------------------------------
__global__ __launch_bounds__(256)
void tail_kernel(const float* __restrict__ Z2,
                 const float* __restrict__ scale2, const float* __restrict__ shift2,
                 const float* __restrict__ W_dfc, const float* __restrict__ b_dfc,
                 const float* __restrict__ W_sw, const float* __restrict__ b_sw,
                 const float* __restrict__ b1, const float* __restrict__ W2,
                 const float* __restrict__ b2, const float* __restrict__ noise,
                 float* __restrict__ out)
{
    __shared__ float sWdfc[kND * kL];
    __shared__ float sWsw[kNP * kL];
    __shared__ float sW2[kNP * kC * kP];
    __shared__ float sb1[kNP * kP];
    __shared__ float sScale[kL];
    __shared__ float sShift[kL];
    const int t = threadIdx.x;
    for (int i = t; i < kND * kL; i += 256) sWdfc[i] = W_dfc[i];
    for (int i = t; i < kNP * kL; i += 256) sWsw[i] = W_sw[i];
    for (int i = t; i < kNP * kC * kP; i += 256) sW2[i] = W2[i];
    for (int i = t; i < kNP * kP; i += 256) sb1[i] = b1[i];
    for (int i = t; i < kL; i += 256) { sScale[i] = scale2[i]; sShift[i] = shift2[i]; }
    __syncthreads();

    const int lane = t & 63;
    const int b = blockIdx.x * 4 + (t >> 6);
    const float* z = Z2 + (size_t)b * kNCAT;

    float d0 = 0.f, d1 = 0.f, s0 = 0.f, s1 = 0.f;
#pragma unroll
    for (int j = 0; j < 6; ++j) {
        const int k = lane + j * 64;
        const float dp = fmaxf(fmaf(z[k], sScale[k], sShift[k]), 0.f);
        d0 = fmaf(dp, sWdfc[k],      d0);
        d1 = fmaf(dp, sWdfc[kL + k], d1);
        s0 = fmaf(dp, sWsw[k],       s0);
        s1 = fmaf(dp, sWsw[kL + k],  s1);
    }
#pragma unroll
    for (int off = 32; off; off >>= 1) {
        d0 += __shfl_xor(d0, off);
        d1 += __shfl_xor(d1, off);
        s0 += __shfl_xor(s0, off);
        s1 += __shfl_xor(s1, off);
    }
    d0 += b_dfc[0];
    d1 += b_dfc[1];

    const float sw0 = fmaxf(s0 + b_sw[0], 0.f);
    const float sw1 = fmaxf(s1 + b_sw[1], 0.f);
    const float l0 = (sw0 + noise[(size_t)b * 2 + 0]) * (1.f / kTAU);
    const float l1 = (sw1 + noise[(size_t)b * 2 + 1]) * (1.f / kTAU);
    const float mx = fmaxf(l0, l1);
    const float e0 = expf(l0 - mx), e1 = expf(l1 - mx);
    const float inv = 1.f / (e0 + e1);
    const float sgum = e0 * inv + e1 * inv;
    const int idx = (l1 > l0) ? 1 : 0;

    const float* zh = z + kL + idx * kP;
    const float h0 = fmaxf(fmaf(zh[lane],       INV_SC2, sb1[idx * kP + lane]),       0.f);
    const float h1 = fmaxf(fmaf(zh[lane + 64],  INV_SC2, sb1[idx * kP + lane + 64]),  0.f);
    const float h2 = fmaxf(fmaf(zh[lane + 128], INV_SC2, sb1[idx * kP + lane + 128]), 0.f);

    float* cop  = out;
    float* dom  = out + (size_t)kB * kC;
    float* idxo = dom + (size_t)kB * kND;

#pragma unroll
    for (int c = 0; c < kC; ++c) {
        const float* wv = &sW2[(idx * kC + c) * kP];
        float oc = h0 * wv[lane] + h1 * wv[lane + 64] + h2 * wv[lane + 128];
#pragma unroll
        for (int off = 32; off; off >>= 1) oc += __shfl_xor(oc, off);
        if (lane == c) cop[(size_t)b * kC + c] = (oc + b2[idx * kC + c]) * sgum;
    }
    if (lane == 0) {
        dom[(size_t)b * 2 + 0] = d0;
        dom[(size_t)b * 2 + 1] = d1;
        idxo[b] = (float)idx;
    }
}

// ---------------------------------------------------------------------------
extern "C" void kernel_launch(void* const* d_in, const int* in_sizes, int n_in,
                              void* d_out, int out_size, void* d_ws, size_t ws_size,
                              hipStream_t stream)
{
    const float* x       = (const float*)d_in[0];
    const float* W_pre   = (const float*)d_in[1];
    // d_in[2] b_pre: cancels exactly through BatchNorm
    const float* g_pre   = (const float*)d_in[3];
    const float* be_pre  = (const float*)d_in[4];
    const float* W_disc  = (const float*)d_in[5];
    // d_in[6] b_disc: cancels through BatchNorm
    const float* g_disc  = (const float*)d_in[7];
    const float* be_disc = (const float*)d_in[8];
    const float* W_dfc   = (const float*)d_in[9];
    const float* b_dfc   = (const float*)d_in[10];
    const float* W_sw    = (const float*)d_in[11];
    const float* b_sw    = (const float*)d_in[12];
    const float* W1      = (const float*)d_in[13];
    const float* b1      = (const float*)d_in[14];
    const float* W2      = (const float*)d_in[15];
    const float* b2      = (const float*)d_in[16];
    const float* noise   = (const float*)d_in[17];

    // workspace layout
    char* wsb = (char*)d_ws;
    unsigned short* Wps = (unsigned short*)wsb;                       // 8.39 MB
    unsigned short* Ws2 = (unsigned short*)(wsb + (size_t)1024 * 4096 * 2);  // 3.15 MB
    float* Z1 = (float*)(wsb + (size_t)1024 * 4096 * 2 + (size_t)768 * 2048 * 2);
    float* Z2 = Z1 + (size_t)kB * kH;
    float* psum1  = Z2 + (size_t)kB * kNCAT;
    float* psq1   = psum1 + (size_t)NPART * kH;
    float* psum2  = psq1 + (size_t)NPART * kH;
    float* psq2   = psum2 + (size_t)NPART * kL;
    float* scale1 = psq2 + (size_t)NPART * kL;
    float* shift1 = scale1 + kH;
    float* scale2 = shift1 + kH;
    float* shift2 = scale2 + kL;
    float* out    = (float*)d_out;

    // 1) pack weights (x64): W_pre [1024,2048]; [W_disc; W1] [768,1024]
    split_pack<<<dim3(kH), 256, 0, stream>>>(W_pre, Wps, kD);
    split_pack<<<dim3(kL), 256, 0, stream>>>(W_disc, Ws2, kH);
    split_pack<<<dim3(kNP * kP), 256, 0, stream>>>(W1, Ws2 + (size_t)kL * (2 * kH), kH);
    // 2) Z1' = 4096 * (x @ W_pre.T), fused column partial stats
    gemm_fused<kD, false><<<dim3(4 * 128), 512, 0, stream>>>(
        x, Wps, nullptr, nullptr, Z1, kH, 4, psum1, psq1, kH);
    // 3) BN1 finalize (outsc=64 folds the feature split pre-scale)
    colstat_finalize<<<dim3(kH / 256), 256, 0, stream>>>(psum1, psq1, kH, g_pre, be_pre,
                                                         scale1, shift1, INV_SC2, SCALE);
    // 4) Z2' = 4096 * (relu(BN(Z1)) @ [W_disc;W1].T), BN fused in staging,
    //    fused partial stats for disc cols (<384)
    gemm_fused<kH, true><<<dim3(3 * 128), 512, 0, stream>>>(
        Z1, Ws2, scale1, shift1, Z2, kNCAT, 3, psum2, psq2, kL);
    // 5) BN2 finalize (outsc=1)
    colstat_finalize<<<dim3((kL + 255) / 256), 256, 0, stream>>>(psum2, psq2, kL, g_disc, be_disc,
                                                                 scale2, shift2, INV_SC2, 1.0f);
    // 6) routing + experts + outputs
    tail_kernel<<<dim3(kB / 4), 256, 0, stream>>>(Z2, scale2, shift2, W_dfc, b_dfc,
                                                  W_sw, b_sw, b1, W2, b2, noise, out);
}

// Round 5
// 671.681 us; speedup vs baseline: 1.0289x; 1.0289x over previous
//
#include <hip/hip_runtime.h>
#include <math.h>

// Problem constants
#define kB 32768
#define kD 2048
#define kH 1024
#define kL 384
#define kP 192
#define kC 10
#define kNP 2
#define kND 2
#define kNCAT 768
#define kTAU 0.1f
#define kEPS 1e-5f
#define NPART 256                 // stats partials: 2 per 256-row block * 128 blocks
#define SCALE 64.0f               // operand pre-scale (keeps f16 lo-plane normal)
#define INV_SC2 (1.0f / 4096.0f)  // GEMM outputs carry SCALE^2

typedef _Float16 f16x8 __attribute__((ext_vector_type(8)));
typedef _Float16 f16x4 __attribute__((ext_vector_type(4)));
typedef float f32x4 __attribute__((ext_vector_type(4)));

#define WAITVM4   asm volatile("s_waitcnt vmcnt(4)" ::: "memory")
#define WAITVM0   asm volatile("s_waitcnt vmcnt(0)" ::: "memory")
#define WAITLGKM0 asm volatile("s_waitcnt lgkmcnt(0)" ::: "memory")

// async global->LDS, 16B per lane (linear LDS dest: base + lane*16)
__device__ __forceinline__ void gll16(const unsigned short* g, unsigned short* l)
{
    __builtin_amdgcn_global_load_lds(
        (const __attribute__((address_space(1))) unsigned int*)g,
        (__attribute__((address_space(3))) unsigned int*)l, 16, 0, 0);
}

// Write-correct bank key: bit0->bit0, bit1->bit2, bit2->bit1.
// Rows 0-3 -> {0,1,4,5}: closed-under-^2 violation broken -> ds_writes
// ({wkey}XOR{0,2} over aligned-4 rows) cover 8 distinct chunk slots.
// Reads (fixed chunk, aligned-8 rows) remain a bijection.
__device__ __host__ __forceinline__ int wkey(int r)
{
    return (r & 1) | ((r & 2) << 1) | ((r & 4) >> 1);
}

// ---------------------------------------------------------------------------
// split_pack (weights only): fp32 [rows][K] -> packed f16 hi/lo planes,
// pre-swizzled. Per 32-k block: 8 chunks of 16B; logical 0..3 hi, 4..7 lo;
// stored chunk = logical ^ wkey(row&7). Values scaled by 64.
// ---------------------------------------------------------------------------
__global__ __launch_bounds__(256)
void split_pack(const float* __restrict__ in, unsigned short* __restrict__ out, int K)
{
    const int row = blockIdx.x;
    const int t = threadIdx.x;
    const int s = wkey(row & 7);
    const float* ir = in + (size_t)row * K;
    unsigned short* orow = out + (size_t)row * (K * 2);
    for (int k0 = t * 4; k0 < K; k0 += 1024) {
        const float4 v = *(const float4*)&ir[k0];
        const float a0 = v.x * SCALE, a1 = v.y * SCALE, a2 = v.z * SCALE, a3 = v.w * SCALE;
        const _Float16 h0 = (_Float16)a0, h1 = (_Float16)a1, h2 = (_Float16)a2, h3 = (_Float16)a3;
        const _Float16 l0 = (_Float16)(a0 - (float)h0), l1 = (_Float16)(a1 - (float)h1);
        const _Float16 l2 = (_Float16)(a2 - (float)h2), l3 = (_Float16)(a3 - (float)h3);
        const f16x4 hi = {h0, h1, h2, h3};
        const f16x4 lo = {l0, l1, l2, l3};
        const int kb = k0 >> 5, kk = k0 & 31;
        const int c = kk >> 3, off = kk & 7;
        *(f16x4*)&orow[kb * 64 + ((c ^ s) << 3) + off]       = hi;
        *(f16x4*)&orow[kb * 64 + (((c ^ 4) ^ s) << 3) + off] = lo;
    }
}

// ---------------------------------------------------------------------------
// Fused split-f16 MFMA GEMM, 256xTILEN tile, 8 waves (2x4), BK=32,
// v_mfma_f32_16x16x32_f16. A: fp32 source reg-staged depth-2 (ping-pong),
// optional fused BN+ReLU (scale/shift broadcast from LDS), split hi/lo,
// conflict-free wkey ds_write at TOP of iteration. B: pre-packed,
// global_load_lds. Double-buffered LDS; counted vmcnt(4) leaves next-tile
// A-loads in flight across the barrier. Epilogue: C + fused column stats.
// ---------------------------------------------------------------------------
template<int KDIM, int TILEN, bool BN>
__global__ __launch_bounds__(512, 1)
void gemm_fused(const float* __restrict__ Afp,
                const unsigned short* __restrict__ Bpk,
                const float* __restrict__ bnsc, const float* __restrict__ bnsh,
                float* __restrict__ C, const int N, const int gridX,
                float* __restrict__ psum, float* __restrict__ psumsq, const int statN)
{
    constexpr int NKB = KDIM / 32;
    constexpr int NI = TILEN / 64;       // 16-col fragments per wave (4 or 2)
    constexpr int BG = TILEN / 64;       // gll16 groups per wave for B
    __shared__ __align__(16) unsigned short As_[2][256 * 64];
    __shared__ __align__(16) unsigned short Bs_[2][TILEN * 64];
    __shared__ float sScL[BN ? KDIM : 1];
    __shared__ float sShL[BN ? KDIM : 1];

    const int t = threadIdx.x;
    const int lane = t & 63;
    const int w = t >> 6;                // 0..7
    const int wr = w >> 2, wc = w & 3;   // 2x4 wave grid; per-wave 128 x (16*NI)
    const int lr = lane & 15, lg = lane >> 4;
    const int ca = (lg ^ wkey(lane & 7)) * 8;   // hi-chunk elem offset; lo = ca^32

    // XCD-chunked swizzle (bijective: nwg % 8 == 0)
    const int nwg = gridDim.x;
    const int chunk = nwg >> 3;
    const int bid = blockIdx.x;
    const int logical = (bid & 7) * chunk + (bid >> 3);
    const int bx = logical % gridX, by = logical / gridX;
    const int m0 = by * 256, n0 = bx * TILEN;

    // A staging geometry: thread -> (row, k-half)
    const int arow = t >> 1;
    const int akh = t & 1;
    const int skey = wkey(arow & 7);
    const int c0 = akh * 2, c1 = akh * 2 + 1;
    const float* aSrc = Afp + (size_t)(m0 + arow) * KDIM + akh * 16;

    // B staging descriptors
    const size_t bstride = (size_t)NKB * 64;
    const unsigned short* bG[BG];
    int bLoff[BG];
#pragma unroll
    for (int it = 0; it < BG; ++it) {
        const int Q = (w * BG + it) * 64 + lane;
        bG[it] = Bpk + (size_t)(n0 + (Q >> 3)) * bstride + (Q & 7) * 8;
        bLoff[it] = (w * BG + it) * 512;
    }

    f32x4 acc[8][NI];
#pragma unroll
    for (int mi = 0; mi < 8; ++mi)
#pragma unroll
        for (int ni = 0; ni < NI; ++ni) acc[mi][ni] = (f32x4){0.f, 0.f, 0.f, 0.f};

    float4 av0[4], av1[4];

    auto issueA = [&](float4 (&av)[4], int kb) {
        const int kt = kb * 32;
#pragma unroll
        for (int j = 0; j < 4; ++j)
            av[j] = *(const float4*)&aSrc[kt + j * 4];
    };

    auto gllB = [&](int kb, int buf) {
#pragma unroll
        for (int it = 0; it < BG; ++it)
            gll16(bG[it] + (size_t)kb * 64, &Bs_[buf][bLoff[it]]);
    };

    auto writeA = [&](const float4 (&av)[4], int buf, int tile) {
        const int kt = tile * 32 + akh * 16;
        float v[16];
#pragma unroll
        for (int j = 0; j < 4; ++j) {
            float4 a = av[j];
            if constexpr (BN) {
                const float4 sc = *(const float4*)&sScL[kt + j * 4];  // broadcast
                const float4 sh = *(const float4*)&sShL[kt + j * 4];
                a.x = fmaxf(fmaf(a.x, sc.x, sh.x), 0.f);
                a.y = fmaxf(fmaf(a.y, sc.y, sh.y), 0.f);
                a.z = fmaxf(fmaf(a.z, sc.z, sh.z), 0.f);
                a.w = fmaxf(fmaf(a.w, sc.w, sh.w), 0.f);
            } else {
                a.x *= SCALE; a.y *= SCALE; a.z *= SCALE; a.w *= SCALE;
            }
            v[j * 4 + 0] = a.x; v[j * 4 + 1] = a.y;
            v[j * 4 + 2] = a.z; v[j * 4 + 3] = a.w;
        }
        f16x8 hi[2], lo[2];
#pragma unroll
        for (int h = 0; h < 2; ++h)
#pragma unroll
            for (int i = 0; i < 8; ++i) {
                const float x = v[h * 8 + i];
                const _Float16 hh = (_Float16)x;
                hi[h][i] = hh;
                lo[h][i] = (_Float16)(x - (float)hh);
            }
        unsigned short* dst = &As_[buf][arow * 64];
        *(f16x8*)&dst[(c0 ^ skey) * 8]       = hi[0];
        *(f16x8*)&dst[(c1 ^ skey) * 8]       = hi[1];
        *(f16x8*)&dst[((c0 ^ 4) ^ skey) * 8] = lo[0];
        *(f16x8*)&dst[((c1 ^ 4) ^ skey) * 8] = lo[1];
    };

    auto body = [&](int kb, const float4 (&avW)[4], float4 (&avI)[4]) {
        const int cur = kb & 1, nxt = cur ^ 1;
        if (kb + 1 < NKB) {
            writeA(avW, nxt, kb + 1);       // data arrived during prev MFMA phase
            gllB(kb + 1, nxt);              // async B -> LDS
        }
        __builtin_amdgcn_sched_barrier(0);  // keep av issues AFTER the glls
        if (kb + 2 < NKB) issueA(avI, kb + 2);

        f16x8 bh[NI], bl[NI];
#pragma unroll
        for (int ni = 0; ni < NI; ++ni) {
            const unsigned short* bb = &Bs_[cur][(wc * (16 * NI) + ni * 16 + lr) * 64];
            bh[ni] = *(const f16x8*)&bb[ca];
            bl[ni] = *(const f16x8*)&bb[ca ^ 32];
        }
#pragma unroll
        for (int mi = 0; mi < 8; ++mi) {
            const unsigned short* ab = &As_[cur][(wr * 128 + mi * 16 + lr) * 64];
            const f16x8 ah = *(const f16x8*)&ab[ca];
            const f16x8 al = *(const f16x8*)&ab[ca ^ 32];
#pragma unroll
            for (int ni = 0; ni < NI; ++ni)
                acc[mi][ni] = __builtin_amdgcn_mfma_f32_16x16x32_f16(ah, bh[ni], acc[mi][ni], 0, 0, 0);
#pragma unroll
            for (int ni = 0; ni < NI; ++ni)
                acc[mi][ni] = __builtin_amdgcn_mfma_f32_16x16x32_f16(ah, bl[ni], acc[mi][ni], 0, 0, 0);
#pragma unroll
            for (int ni = 0; ni < NI; ++ni)
                acc[mi][ni] = __builtin_amdgcn_mfma_f32_16x16x32_f16(al, bh[ni], acc[mi][ni], 0, 0, 0);
        }
        if (kb + 1 < NKB) {
            if (kb + 2 < NKB) { WAITVM4; } else { WAITVM0; }  // glls done; avI flies
            WAITLGKM0;
            __builtin_amdgcn_sched_barrier(0);
            __builtin_amdgcn_s_barrier();
            __builtin_amdgcn_sched_barrier(0);
        }
    };

    // ---- prologue ----
    if constexpr (BN) {
        if (t < KDIM / 4) {
            ((float4*)sScL)[t] = ((const float4*)bnsc)[t];
            ((float4*)sShL)[t] = ((const float4*)bnsh)[t];
        }
        __syncthreads();
    }
    issueA(av0, 0);
    gllB(0, 0);
    __builtin_amdgcn_sched_barrier(0);
    issueA(av1, 1);
    writeA(av0, 0, 0);                     // waits av0 only
    WAITVM4;                               // gll(0) done; av1 in flight
    WAITLGKM0;
    __builtin_amdgcn_sched_barrier(0);
    __builtin_amdgcn_s_barrier();
    __builtin_amdgcn_sched_barrier(0);

    for (int kb = 0; kb < NKB; kb += 2) {
        body(kb,     av1, av0);
        body(kb + 1, av0, av1);
    }

    // C store (C/D layout: col = lane&15, row = (lane>>4)*4 + j)
#pragma unroll
    for (int mi = 0; mi < 8; ++mi)
#pragma unroll
        for (int j = 0; j < 4; ++j) {
            const int row = m0 + wr * 128 + mi * 16 + lg * 4 + j;
            float* cr = C + (size_t)row * N + n0 + wc * (16 * NI) + lr;
#pragma unroll
            for (int ni = 0; ni < NI; ++ni) cr[ni * 16] = acc[mi][ni][j];
        }

    // fused column partial stats over this wave's 128 rows
#pragma unroll
    for (int ni = 0; ni < NI; ++ni) {
        float s = 0.f, sq = 0.f;
#pragma unroll
        for (int mi = 0; mi < 8; ++mi)
#pragma unroll
            for (int j = 0; j < 4; ++j) {
                const float v = acc[mi][ni][j];
                s += v;
                sq = fmaf(v, v, sq);
            }
        s  += __shfl_xor(s, 16);  s  += __shfl_xor(s, 32);
        sq += __shfl_xor(sq, 16); sq += __shfl_xor(sq, 32);
        const int col = n0 + wc * (16 * NI) + ni * 16 + lr;
        if (lane < 16 && col < statN) {
            psum[(size_t)(by * 2 + wr) * statN + col]   = s;
            psumsq[(size_t)(by * 2 + wr) * statN + col] = sq;
        }
    }
}

// ---------------------------------------------------------------------------
// finalize: input partials of Z' = Z/inv_sc; output scale/shift s.t.
// Z'*scale + shift == outsc * (BN(Z)*g + be)
// ---------------------------------------------------------------------------
__global__ __launch_bounds__(256)
void colstat_finalize(const float* __restrict__ psum, const float* __restrict__ psumsq,
                      int ncols, const float* __restrict__ g, const float* __restrict__ be,
                      float* __restrict__ scale, float* __restrict__ shift,
                      float inv_sc, float outsc)
{
    const int c = blockIdx.x * 256 + threadIdx.x;
    if (c >= ncols) return;
    float s = 0.f, sq = 0.f;
    for (int i = 0; i < NPART; ++i) {
        s  += psum[(size_t)i * ncols + c];
        sq += psumsq[(size_t)i * ncols + c];
    }
    const float mup = s * (1.f / kB);
    const float var = (sq * (1.f / kB) - mup * mup) * inv_sc * inv_sc;
    const float scl = outsc * g[c] * rsqrtf(var + kEPS) * inv_sc;
    scale[c] = scl;
    shift[c] = fmaf(-mup, scl, outsc * be[c]);
}

// ---------------------------------------------------------------------------
// Tail: per-row BN2+ReLU -> dom, sw, gumbel routing, selected expert.
// ---------------------------------------------------------------------------
__global__ __launch_bounds__(256)
void tail_kernel(const float* __restrict__ Z2,
                 const float* __restrict__ scale2, const float* __restrict__ shift2,
                 const float* __restrict__ W_dfc, const float* __restrict__ b_dfc,
                 const float* __restrict__ W_sw, const float* __restrict__ b_sw,
                 const float* __restrict__ b1, const float* __restrict__ W2,
                 const float* __restrict__ b2, const float* __restrict__ noise,
                 float* __restrict__ out)
{
    __shared__ float sWdfc[kND * kL];
    __shared__ float sWsw[kNP * kL];
    __shared__ float sW2[kNP * kC * kP];
    __shared__ float sb1[kNP * kP];
    __shared__ float sScale[kL];
    __shared__ float sShift[kL];
    const int t = threadIdx.x;
    for (int i = t; i < kND * kL; i += 256) sWdfc[i] = W_dfc[i];
    for (int i = t; i < kNP * kL; i += 256) sWsw[i] = W_sw[i];
    for (int i = t; i < kNP * kC * kP; i += 256) sW2[i] = W2[i];
    for (int i = t; i < kNP * kP; i += 256) sb1[i] = b1[i];
    for (int i = t; i < kL; i += 256) { sScale[i] = scale2[i]; sShift[i] = shift2[i]; }
    __syncthreads();

    const int lane = t & 63;
    const int b = blockIdx.x * 4 + (t >> 6);
    const float* z = Z2 + (size_t)b * kNCAT;

    float d0 = 0.f, d1 = 0.f, s0 = 0.f, s1 = 0.f;
#pragma unroll
    for (int j = 0; j < 6; ++j) {
        const int k = lane + j * 64;
        const float dp = fmaxf(fmaf(z[k], sScale[k], sShift[k]), 0.f);
        d0 = fmaf(dp, sWdfc[k],      d0);
        d1 = fmaf(dp, sWdfc[kL + k], d1);
        s0 = fmaf(dp, sWsw[k],       s0);
        s1 = fmaf(dp, sWsw[kL + k],  s1);
    }
#pragma unroll
    for (int off = 32; off; off >>= 1) {
        d0 += __shfl_xor(d0, off);
        d1 += __shfl_xor(d1, off);
        s0 += __shfl_xor(s0, off);
        s1 += __shfl_xor(s1, off);
    }
    d0 += b_dfc[0];
    d1 += b_dfc[1];

    const float sw0 = fmaxf(s0 + b_sw[0], 0.f);
    const float sw1 = fmaxf(s1 + b_sw[1], 0.f);
    const float l0 = (sw0 + noise[(size_t)b * 2 + 0]) * (1.f / kTAU);
    const float l1 = (sw1 + noise[(size_t)b * 2 + 1]) * (1.f / kTAU);
    const float mx = fmaxf(l0, l1);
    const float e0 = expf(l0 - mx), e1 = expf(l1 - mx);
    const float inv = 1.f / (e0 + e1);
    const float sgum = e0 * inv + e1 * inv;
    const int idx = (l1 > l0) ? 1 : 0;

    const float* zh = z + kL + idx * kP;
    const float h0 = fmaxf(fmaf(zh[lane],       INV_SC2, sb1[idx * kP + lane]),       0.f);
    const float h1 = fmaxf(fmaf(zh[lane + 64],  INV_SC2, sb1[idx * kP + lane + 64]),  0.f);
    const float h2 = fmaxf(fmaf(zh[lane + 128], INV_SC2, sb1[idx * kP + lane + 128]), 0.f);

    float* cop  = out;
    float* dom  = out + (size_t)kB * kC;
    float* idxo = dom + (size_t)kB * kND;

#pragma unroll
    for (int c = 0; c < kC; ++c) {
        const float* wv = &sW2[(idx * kC + c) * kP];
        float oc = h0 * wv[lane] + h1 * wv[lane + 64] + h2 * wv[lane + 128];
#pragma unroll
        for (int off = 32; off; off >>= 1) oc += __shfl_xor(oc, off);
        if (lane == c) cop[(size_t)b * kC + c] = (oc + b2[idx * kC + c]) * sgum;
    }
    if (lane == 0) {
        dom[(size_t)b * 2 + 0] = d0;
        dom[(size_t)b * 2 + 1] = d1;
        idxo[b] = (float)idx;
    }
}

// ---------------------------------------------------------------------------
extern "C" void kernel_launch(void* const* d_in, const int* in_sizes, int n_in,
                              void* d_out, int out_size, void* d_ws, size_t ws_size,
                              hipStream_t stream)
{
    const float* x       = (const float*)d_in[0];
    const float* W_pre   = (const float*)d_in[1];
    // d_in[2] b_pre: cancels exactly through BatchNorm
    const float* g_pre   = (const float*)d_in[3];
    const float* be_pre  = (const float*)d_in[4];
    const float* W_disc  = (const float*)d_in[5];
    // d_in[6] b_disc: cancels through BatchNorm
    const float* g_disc  = (const float*)d_in[7];
    const float* be_disc = (const float*)d_in[8];
    const float* W_dfc   = (const float*)d_in[9];
    const float* b_dfc   = (const float*)d_in[10];
    const float* W_sw    = (const float*)d_in[11];
    const float* b_sw    = (const float*)d_in[12];
    const float* W1      = (const float*)d_in[13];
    const float* b1      = (const float*)d_in[14];
    const float* W2      = (const float*)d_in[15];
    const float* b2      = (const float*)d_in[16];
    const float* noise   = (const float*)d_in[17];

    // workspace layout
    char* wsb = (char*)d_ws;
    unsigned short* Wps = (unsigned short*)wsb;                              // 8.39 MB
    unsigned short* Ws2 = (unsigned short*)(wsb + (size_t)1024 * 4096 * 2);  // 3.15 MB
    float* Z1 = (float*)(wsb + (size_t)1024 * 4096 * 2 + (size_t)768 * 2048 * 2);
    float* Z2 = Z1 + (size_t)kB * kH;
    float* psum1  = Z2 + (size_t)kB * kNCAT;
    float* psq1   = psum1 + (size_t)NPART * kH;
    float* psum2  = psq1 + (size_t)NPART * kH;
    float* psq2   = psum2 + (size_t)NPART * kL;
    float* scale1 = psq2 + (size_t)NPART * kL;
    float* shift1 = scale1 + kH;
    float* scale2 = shift1 + kH;
    float* shift2 = scale2 + kL;
    float* out    = (float*)d_out;

    // 1) pack weights (x64): W_pre [1024,2048]; [W_disc; W1] [768,1024]
    split_pack<<<dim3(kH), 256, 0, stream>>>(W_pre, Wps, kD);
    split_pack<<<dim3(kL), 256, 0, stream>>>(W_disc, Ws2, kH);
    split_pack<<<dim3(kNP * kP), 256, 0, stream>>>(W1, Ws2 + (size_t)kL * (2 * kH), kH);
    // 2) Z1' = 4096 * (x @ W_pre.T), fused column partial stats
    gemm_fused<kD, 256, false><<<dim3(4 * 128), 512, 0, stream>>>(
        x, Wps, nullptr, nullptr, Z1, kH, 4, psum1, psq1, kH);
    // 3) BN1 finalize (outsc=64 folds the feature split pre-scale)
    colstat_finalize<<<dim3(kH / 256), 256, 0, stream>>>(psum1, psq1, kH, g_pre, be_pre,
                                                         scale1, shift1, INV_SC2, SCALE);
    // 4) Z2' = 4096 * (relu(BN(Z1)) @ [W_disc;W1].T), BN fused in staging,
    //    256x128 tile -> 768 blocks = 3 exact CU rounds
    gemm_fused<kH, 128, true><<<dim3(6 * 128), 512, 0, stream>>>(
        Z1, Ws2, scale1, shift1, Z2, kNCAT, 6, psum2, psq2, kL);
    // 5) BN2 finalize (outsc=1)
    colstat_finalize<<<dim3((kL + 255) / 256), 256, 0, stream>>>(psum2, psq2, kL, g_disc, be_disc,
                                                                 scale2, shift2, INV_SC2, 1.0f);
    // 6) routing + experts + outputs
    tail_kernel<<<dim3(kB / 4), 256, 0, stream>>>(Z2, scale2, shift2, W_dfc, b_dfc,
                                                  W_sw, b_sw, b1, W2, b2, noise, out);
}